// Round 6
// baseline (103.399 us; speedup 1.0000x reference)
//
#include <hip/hip_runtime.h>
#include <math.h>

#define EPSF 1e-5f
#define SINKHORN_ITERS 20
#define C_DIM 4096
#define N_DIM 4

typedef __attribute__((ext_vector_type(4))) float fx4;

// Kernel 1: tiny prep — sigmoids + sinkhorn on 4x4. params layout:
// [0..3] = sigmoid(H_pre), [4..7] = 2*sigmoid(H_post), [8..23] = M row-major.
// R4 lesson: this MUST stay a separate 1-thread kernel — folding it into the
// fused kernel made every wave pay a ~3.2k-cycle serial rcp chain (VALUBusy
// 97%, +50us).
__global__ void prep_kernel(const float* __restrict__ H_pre,
                            const float* __restrict__ H_post,
                            const float* __restrict__ H_res,
                            float* __restrict__ params) {
    if (threadIdx.x != 0 || blockIdx.x != 0) return;
    float M[4][4];
    for (int i = 0; i < 4; ++i)
        for (int j = 0; j < 4; ++j)
            M[i][j] = expf(H_res[i * 4 + j]);
    for (int it = 0; it < SINKHORN_ITERS; ++it) {
        for (int i = 0; i < 4; ++i) {       // row normalize (axis=1)
            float s = M[i][0] + M[i][1] + M[i][2] + M[i][3] + EPSF;
            M[i][0] /= s; M[i][1] /= s; M[i][2] /= s; M[i][3] /= s;
        }
        for (int j = 0; j < 4; ++j) {       // col normalize (axis=0)
            float s = M[0][j] + M[1][j] + M[2][j] + M[3][j] + EPSF;
            M[0][j] /= s; M[1][j] /= s; M[2][j] /= s; M[3][j] /= s;
        }
    }
    for (int i = 0; i < 4; ++i) {
        params[i]     = 1.0f / (1.0f + expf(-H_pre[i]));
        params[4 + i] = 2.0f / (1.0f + expf(-H_post[i]));
    }
    for (int i = 0; i < 4; ++i)
        for (int j = 0; j < 4; ++j)
            params[8 + i * 4 + j] = M[i][j];
}

// Kernel 2: one block (512 threads, 8 waves) per batch row b.
// Thread t owns columns {k*2048 + t*4 .. +3} for k=0..1 across all 4
// expansion rows. Single __syncthreads for the RMS reduce.
//
// Cache policy (R4/R5 counter evidence): plain cacheable LOADS — x is never
// mutated, L3 retains ~half of it across replays (FETCH=128MB). Nontemporal
// STORES — the 256MB output stream must not evict x from L3.
//
// __launch_bounds__(512, 4): R5's (512,8) clamped the allocator to 32 VGPRs,
// forcing the x-tile (32 VGPRs by itself) to be re-loaded after the barrier.
// Cap 128 lets all 8 float4s stay live load->store; 4 blocks/CU still fit
// (R3 proved >16 waves/CU buys nothing here).
__global__ __launch_bounds__(512, 4)
void fused_kernel(const float* __restrict__ x,
                  const float* __restrict__ w,
                  const float* __restrict__ params,
                  float* __restrict__ out) {
    const int b = blockIdx.x;
    const int t = threadIdx.x;

    // uniform indices -> scalar (s_load) broadcast, zero VGPR cost
    const float p0 = params[0], p1 = params[1], p2 = params[2], p3 = params[3];

    const size_t base = (size_t)b * (N_DIM * C_DIM);
    const int c0 = t * 4;

    // Load x[b, i, k*2048 + c0 .. +3] — 8 float4 in flight, cacheable.
    fx4 xv[4][2];   // [row i][chunk k]
    #pragma unroll
    for (int i = 0; i < 4; ++i)
        #pragma unroll
        for (int k = 0; k < 2; ++k)
            xv[i][k] = *reinterpret_cast<const fx4*>(
                x + base + i * C_DIM + k * 2048 + c0);

    // aggregate + sum of squares (agg recomputed later; only ss kept)
    float ss = 0.0f;
    #pragma unroll
    for (int k = 0; k < 2; ++k) {
        fx4 a = p0 * xv[0][k] + p1 * xv[1][k] + p2 * xv[2][k] + p3 * xv[3][k];
        ss += a.x * a.x + a.y * a.y + a.z * a.z + a.w * a.w;
    }

    // wave64 reduce -> 8 partials -> every thread sums them (one barrier)
    #pragma unroll
    for (int off = 32; off > 0; off >>= 1)
        ss += __shfl_down(ss, off, 64);
    __shared__ float sp[8];
    if ((t & 63) == 0) sp[t >> 6] = ss;
    __syncthreads();
    const float tot = sp[0] + sp[1] + sp[2] + sp[3]
                    + sp[4] + sp[5] + sp[6] + sp[7];
    const float inv = 1.0f / sqrtf(tot * (1.0f / (float)C_DIM) + EPSF);

    // output: out[b,i,c] = sum_j M[i][j] x[b,j,c] + post_i * (agg*inv*w)
    #pragma unroll
    for (int k = 0; k < 2; ++k) {
        fx4 wv = *reinterpret_cast<const fx4*>(w + k * 2048 + c0);  // L2-hot
        fx4 a = p0 * xv[0][k] + p1 * xv[1][k] + p2 * xv[2][k] + p3 * xv[3][k];
        fx4 nw = a * inv * wv;
        #pragma unroll
        for (int i = 0; i < 4; ++i) {
            const float m0 = params[8 + i * 4 + 0];
            const float m1 = params[8 + i * 4 + 1];
            const float m2 = params[8 + i * 4 + 2];
            const float m3 = params[8 + i * 4 + 3];
            const float po = params[4 + i];
            fx4 o = m0 * xv[0][k] + m1 * xv[1][k] + m2 * xv[2][k] + m3 * xv[3][k]
                  + po * nw;
            __builtin_nontemporal_store(
                o, reinterpret_cast<fx4*>(out + base + i * C_DIM + k * 2048 + c0));
        }
    }
}

extern "C" void kernel_launch(void* const* d_in, const int* in_sizes, int n_in,
                              void* d_out, int out_size, void* d_ws, size_t ws_size,
                              hipStream_t stream) {
    const float* x      = (const float*)d_in[0];
    const float* w      = (const float*)d_in[1];
    const float* H_pre  = (const float*)d_in[2];
    const float* H_post = (const float*)d_in[3];
    const float* H_res  = (const float*)d_in[4];
    float* out    = (float*)d_out;
    float* params = (float*)d_ws;

    const int B = in_sizes[0] / (N_DIM * C_DIM);  // 4096

    prep_kernel<<<1, 64, 0, stream>>>(H_pre, H_post, H_res, params);
    fused_kernel<<<B, 512, 0, stream>>>(x, w, params, out);
}

// Round 7
// 102.559 us; speedup vs baseline: 1.0082x; 1.0082x over previous
//
#include <hip/hip_runtime.h>
#include <math.h>

#define EPSF 1e-5f
#define SINKHORN_ITERS 20
#define C_DIM 4096
#define N_DIM 4

typedef __attribute__((ext_vector_type(4))) float fx4;

// Kernel 1: tiny prep — sigmoids + sinkhorn on 4x4. params layout:
// [0..3] = sigmoid(H_pre), [4..7] = 2*sigmoid(H_post), [8..23] = M row-major.
// R4 lesson: this MUST stay a separate 1-thread kernel — folding it into the
// fused kernel made every wave pay a ~3.2k-cycle serial rcp chain (VALUBusy
// 97%, +50us).
__global__ void prep_kernel(const float* __restrict__ H_pre,
                            const float* __restrict__ H_post,
                            const float* __restrict__ H_res,
                            float* __restrict__ params) {
    if (threadIdx.x != 0 || blockIdx.x != 0) return;
    float M[4][4];
    for (int i = 0; i < 4; ++i)
        for (int j = 0; j < 4; ++j)
            M[i][j] = expf(H_res[i * 4 + j]);
    for (int it = 0; it < SINKHORN_ITERS; ++it) {
        for (int i = 0; i < 4; ++i) {       // row normalize (axis=1)
            float s = M[i][0] + M[i][1] + M[i][2] + M[i][3] + EPSF;
            M[i][0] /= s; M[i][1] /= s; M[i][2] /= s; M[i][3] /= s;
        }
        for (int j = 0; j < 4; ++j) {       // col normalize (axis=0)
            float s = M[0][j] + M[1][j] + M[2][j] + M[3][j] + EPSF;
            M[0][j] /= s; M[1][j] /= s; M[2][j] /= s; M[3][j] /= s;
        }
    }
    for (int i = 0; i < 4; ++i) {
        params[i]     = 1.0f / (1.0f + expf(-H_pre[i]));
        params[4 + i] = 2.0f / (1.0f + expf(-H_post[i]));
    }
    for (int i = 0; i < 4; ++i)
        for (int j = 0; j < 4; ++j)
            params[8 + i * 4 + j] = M[i][j];
}

// Kernel 2: one block (512 threads, 8 waves) per batch row b.
// Thread t owns columns {k*2048 + t*4 .. +3} for k=0..1 across all 4
// expansion rows. Single __syncthreads for the RMS reduce.
//
// Cache policy (R4/R5 counter evidence): plain cacheable LOADS — x is never
// mutated, L3 retains much of it across replays (FETCH=128MB profiled).
// Nontemporal STORES — the 256MB output stream must not evict x from L3.
//
// R6 lesson: without the asm pin below, the compiler load-sinks the x-tile
// past the barrier (VGPR_Count=32 even with cap 128) and re-reads 256MB from
// L2 in the store phase. The empty "+v" asm makes the loaded values opaque —
// they cannot be rematerialized, so x stays in VGPRs load->store.
__global__ __launch_bounds__(512, 4)
void fused_kernel(const float* __restrict__ x,
                  const float* __restrict__ w,
                  const float* __restrict__ params,
                  float* __restrict__ out) {
    const int b = blockIdx.x;
    const int t = threadIdx.x;

    // uniform indices -> scalar (s_load) broadcast, zero VGPR cost
    const float p0 = params[0], p1 = params[1], p2 = params[2], p3 = params[3];

    const size_t base = (size_t)b * (N_DIM * C_DIM);
    const int c0 = t * 4;

    // Load x[b, i, k*2048 + c0 .. +3] — 8 float4 in flight, cacheable.
    fx4 xv[4][2];   // [row i][chunk k]
    #pragma unroll
    for (int i = 0; i < 4; ++i)
        #pragma unroll
        for (int k = 0; k < 2; ++k)
            xv[i][k] = *reinterpret_cast<const fx4*>(
                x + base + i * C_DIM + k * 2048 + c0);

    // w is L2-hot (16KB shared by all blocks) — issue pre-barrier too.
    fx4 wv[2];
    #pragma unroll
    for (int k = 0; k < 2; ++k)
        wv[k] = *reinterpret_cast<const fx4*>(w + k * 2048 + c0);

    // Pin: forbid rematerialization/load-sinking of the x-tile and w.
    #pragma unroll
    for (int i = 0; i < 4; ++i)
        #pragma unroll
        for (int k = 0; k < 2; ++k)
            asm volatile("" : "+v"(xv[i][k]));
    #pragma unroll
    for (int k = 0; k < 2; ++k)
        asm volatile("" : "+v"(wv[k]));

    // aggregate + sum of squares (agg recomputed later; only ss kept)
    float ss = 0.0f;
    #pragma unroll
    for (int k = 0; k < 2; ++k) {
        fx4 a = p0 * xv[0][k] + p1 * xv[1][k] + p2 * xv[2][k] + p3 * xv[3][k];
        ss += a.x * a.x + a.y * a.y + a.z * a.z + a.w * a.w;
    }

    // wave64 reduce -> 8 partials -> every thread sums them (one barrier)
    #pragma unroll
    for (int off = 32; off > 0; off >>= 1)
        ss += __shfl_down(ss, off, 64);
    __shared__ float sp[8];
    if ((t & 63) == 0) sp[t >> 6] = ss;
    __syncthreads();
    const float tot = sp[0] + sp[1] + sp[2] + sp[3]
                    + sp[4] + sp[5] + sp[6] + sp[7];
    const float inv = 1.0f / sqrtf(tot * (1.0f / (float)C_DIM) + EPSF);

    // output: out[b,i,c] = sum_j M[i][j] x[b,j,c] + post_i * (agg*inv*w)
    // pure register math + stores — no loads in this phase
    #pragma unroll
    for (int k = 0; k < 2; ++k) {
        fx4 a = p0 * xv[0][k] + p1 * xv[1][k] + p2 * xv[2][k] + p3 * xv[3][k];
        fx4 nw = a * inv * wv[k];
        #pragma unroll
        for (int i = 0; i < 4; ++i) {
            const float m0 = params[8 + i * 4 + 0];
            const float m1 = params[8 + i * 4 + 1];
            const float m2 = params[8 + i * 4 + 2];
            const float m3 = params[8 + i * 4 + 3];
            const float po = params[4 + i];
            fx4 o = m0 * xv[0][k] + m1 * xv[1][k] + m2 * xv[2][k] + m3 * xv[3][k]
                  + po * nw;
            __builtin_nontemporal_store(
                o, reinterpret_cast<fx4*>(out + base + i * C_DIM + k * 2048 + c0));
        }
    }
}

extern "C" void kernel_launch(void* const* d_in, const int* in_sizes, int n_in,
                              void* d_out, int out_size, void* d_ws, size_t ws_size,
                              hipStream_t stream) {
    const float* x      = (const float*)d_in[0];
    const float* w      = (const float*)d_in[1];
    const float* H_pre  = (const float*)d_in[2];
    const float* H_post = (const float*)d_in[3];
    const float* H_res  = (const float*)d_in[4];
    float* out    = (float*)d_out;
    float* params = (float*)d_ws;

    const int B = in_sizes[0] / (N_DIM * C_DIM);  // 4096

    prep_kernel<<<1, 64, 0, stream>>>(H_pre, H_post, H_res, params);
    fused_kernel<<<B, 512, 0, stream>>>(x, w, params, out);
}